// Round 6
// baseline (8471.858 us; speedup 1.0000x reference)
//
#include <hip/hip_runtime.h>

typedef _Float16 h2 __attribute__((ext_vector_type(2)));

__device__ __forceinline__ h2 mkh2(float a, float b) {
    h2 r; r.x = (_Float16)a; r.y = (_Float16)b; return r;
}
__device__ __forceinline__ h2 bc(unsigned u) {
    union { unsigned u; h2 h; } c; c.u = u; return c.h;
}

// DPP quad-perm lane exchange (VALU, no LDS): 0xB1 = swap lane^1
template <int CTRL>
__device__ __forceinline__ float dpp_q(float v) {
    int i = __builtin_bit_cast(int, v);
    int r = __builtin_amdgcn_update_dpp(0, i, CTRL, 0xF, 0xF, true);
    return __builtin_bit_cast(float, r);
}

// Barrier that drains ONLY LDS ops (lgkmcnt), leaving global prefetches
// (vmcnt) in flight.
#define BARRIER() asm volatile("s_waitcnt lgkmcnt(0)\n\ts_barrier" ::: "memory")

// 8 fdot2: one uint4 of h (8 halves) against row-A and row-B weight pairs.
#define DOT8(Q, i) do {                                               \
    aA0 = __builtin_amdgcn_fdot2(WA[4*i+0], bc(Q.x), aA0, false);     \
    aA1 = __builtin_amdgcn_fdot2(WA[4*i+1], bc(Q.y), aA1, false);     \
    aA2 = __builtin_amdgcn_fdot2(WA[4*i+2], bc(Q.z), aA2, false);     \
    aA3 = __builtin_amdgcn_fdot2(WA[4*i+3], bc(Q.w), aA3, false);     \
    aB0 = __builtin_amdgcn_fdot2(WB[4*i+0], bc(Q.x), aB0, false);     \
    aB1 = __builtin_amdgcn_fdot2(WB[4*i+1], bc(Q.y), aB1, false);     \
    aB2 = __builtin_amdgcn_fdot2(WB[4*i+2], bc(Q.z), aB2, false);     \
    aB3 = __builtin_amdgcn_fdot2(WB[4*i+3], bc(Q.w), aB3, false);     \
} while (0)

// Keep a 12-element slice of a h2 array pinned in VGPRs at this point.
#define PIN12(W, o) asm("" : "+v"(W[o+0]), "+v"(W[o+1]), "+v"(W[o+2]),  \
                         "+v"(W[o+3]), "+v"(W[o+4]), "+v"(W[o+5]),      \
                         "+v"(W[o+6]), "+v"(W[o+7]), "+v"(W[o+8]),      \
                         "+v"(W[o+9]), "+v"(W[o+10]), "+v"(W[o+11]))

// 96-wide f32 dot of one LDS history row against w_dense.
__device__ __forceinline__ float head_dot(const float* hrow, const float* wdp) {
    const float4* hr = reinterpret_cast<const float4*>(hrow);
    const float4* wv = reinterpret_cast<const float4*>(wdp);
    float a0 = 0.f, a1 = 0.f, a2 = 0.f, a3 = 0.f;
    #pragma unroll
    for (int k = 0; k < 24; k += 4) {
        float4 ha = hr[k], hb = hr[k + 1], hc = hr[k + 2], hd = hr[k + 3];
        float4 wa = wv[k], wb = wv[k + 1], wc = wv[k + 2], wd = wv[k + 3];
        a0 = fmaf(ha.w, wa.w, fmaf(ha.z, wa.z, fmaf(ha.y, wa.y, fmaf(ha.x, wa.x, a0))));
        a1 = fmaf(hb.w, wb.w, fmaf(hb.z, wb.z, fmaf(hb.y, wb.y, fmaf(hb.x, wb.x, a1))));
        a2 = fmaf(hc.w, wc.w, fmaf(hc.z, wc.z, fmaf(hc.y, wc.y, fmaf(hc.x, wc.x, a2))));
        a3 = fmaf(hd.w, wd.w, fmaf(hd.z, wd.z, fmaf(hd.y, wd.y, fmaf(hd.x, wd.x, a3))));
    }
    return (a0 + a1) + (a2 + a3);
}

// 3 waves, each lane owns TWO w_hh rows. Lane (u, p): u = 32*wv + (lane>>1),
// p = lane&1.
//   p==0 computes rows u (i, sigmoid)      and 192+u (g, tanh)
//   p==1 computes rows 96+u (f, sigmoid)   and 288+u (o, sigmoid)
// One DPP xor1 swap delivers (f,o) to the p==0 lane, which owns c/h of unit u.
// The dense head runs as a 64-step burst split across all 3 waves.
__global__ __launch_bounds__(192, 1)
void lstm_fused(
    const float* __restrict__ x,        // [B,T]
    const float* __restrict__ w_ih,     // [384]
    const float* __restrict__ w_hh,     // [384,96]
    const float* __restrict__ b_ih,     // [384]
    const float* __restrict__ b_hh,     // [384]
    const float* __restrict__ w_dense,  // [96]
    const float* __restrict__ b_dense,  // [1]
    float* __restrict__ out,            // [B,T]
    int T)
{
    const int tid  = threadIdx.x;    // 0..191
    const int lane = tid & 63;
    const int wv   = tid >> 6;       // 0..2

    // Double-buffered h (f16, broadcast-read).
    __shared__ __align__(16) _Float16 hbuf[2][96];
    // 64-step h history (f32) for the dense head.
    __shared__ __align__(16) float hist[2][64][100];

    if (tid < 96) { hbuf[0][tid] = (_Float16)0.f; hbuf[1][tid] = (_Float16)0.f; }

    const float* xrow = x + (size_t)blockIdx.x * T;
    float*       orow = out + (size_t)blockIdx.x * T;

    const int p = lane & 1;
    const int u = (wv << 5) | (lane >> 1);   // hidden unit 0..95
    const int rowA = 96 * p + u;             // p0: i-row, p1: f-row
    const int rowB = 96 * (2 + p) + u;       // p0: g-row, p1: o-row

    // Weights for both rows as packed-f16 pairs in VGPRs (48 + 48 h2).
    h2 WA[48], WB[48];
    {
        const float4* ra = reinterpret_cast<const float4*>(w_hh + (size_t)rowA * 96);
        const float4* rb = reinterpret_cast<const float4*>(w_hh + (size_t)rowB * 96);
        #pragma unroll
        for (int q = 0; q < 24; ++q) {
            float4 fa = ra[q];
            WA[2*q]   = mkh2(fa.x, fa.y);
            WA[2*q+1] = mkh2(fa.z, fa.w);
        }
        #pragma unroll
        for (int q = 0; q < 24; ++q) {
            float4 fb = rb[q];
            WB[2*q]   = mkh2(fb.x, fb.y);
            WB[2*q+1] = mkh2(fb.z, fb.w);
        }
    }

    const float wihA  = w_ih[rowA];
    const float wihB  = w_ih[rowB];
    const float biasA = b_ih[rowA] + b_hh[rowA];
    const float biasB = b_ih[rowB] + b_hh[rowB];
    // Row B is tanh only for p==0 (gate g): tanh(x) = 2*sig(2x)-1.
    const float nkB = (p == 0) ? -2.885390082f : -1.442695041f;
    const float m1B = (p == 0) ? 2.f : 1.f;
    const float d1B = (p == 0) ? -1.f : 0.f;

    // Head-burst row assignment: row r = 3*lane + wv (64 rows over 3 waves).
    const int hrow    = 3 * lane + wv;
    const bool hactive = (hrow < 64);
    const float bd = b_dense[0];

    float c  = 0.f;
    float xs = xrow[0];

    __syncthreads();

    #pragma unroll 1
    for (int t = 0; t < T; ++t) {
        // Re-pin the weight registers each iteration: prevents the compiler
        // from rematerializing them from global memory inside the loop.
        PIN12(WA, 0); PIN12(WA, 12); PIN12(WA, 24); PIN12(WA, 36);
        PIN12(WB, 0); PIN12(WB, 12); PIN12(WB, 24); PIN12(WB, 36);

        // Head burst: once per 64 steps, all waves drain the completed window.
        if (t && (t & 63) == 0) {
            if (hactive) {
                const int buf = ((t >> 6) - 1) & 1;
                float a = head_dot(&hist[buf][hrow][0], w_dense);
                orow[t - 64 + hrow] = a + bd;
            }
        }

        int tn = (t + 1 < T) ? t + 1 : T - 1;
        float xs_n = xrow[tn];

        const uint4* hp = reinterpret_cast<const uint4*>(hbuf[(t & 1) ^ 1]);
        float aA0 = 0.f, aA1 = 0.f, aA2 = 0.f, aA3 = 0.f;
        float aB0 = 0.f, aB1 = 0.f, aB2 = 0.f, aB3 = 0.f;
        uint4 qA = hp[0], qB = hp[1], qC = hp[2];
        DOT8(qA, 0);  qA = hp[3];
        DOT8(qB, 1);  qB = hp[4];
        DOT8(qC, 2);  qC = hp[5];
        DOT8(qA, 3);  qA = hp[6];
        DOT8(qB, 4);  qB = hp[7];
        DOT8(qC, 5);  qC = hp[8];
        DOT8(qA, 6);  qA = hp[9];
        DOT8(qB, 7);  qB = hp[10];
        DOT8(qC, 8);  qC = hp[11];
        DOT8(qA, 9);
        DOT8(qB, 10);
        DOT8(qC, 11);

        float vA = (aA0 + aA1) + (aA2 + aA3);
        float vB = (aB0 + aB1) + (aB2 + aB3);
        float preA = vA + fmaf(xs, wihA, biasA);
        float preB = vB + fmaf(xs, wihB, biasB);
        // row A is always sigmoid
        float actA = __builtin_amdgcn_rcpf(1.f + __builtin_exp2f(preA * -1.442695041f));
        float actB = fmaf(m1B, __builtin_amdgcn_rcpf(1.f + __builtin_exp2f(preB * nkB)), d1B);

        // pair swap: p0 receives (f, o) from p1
        float oA = dpp_q<0xB1>(actA);
        float oB = dpp_q<0xB1>(actB);

        if (p == 0) {   // owns unit u: actA=i, actB=g, oA=f, oB=o
            c = fmaf(oA, c, actA * actB);
            float th = fmaf(2.f, __builtin_amdgcn_rcpf(1.f + __builtin_exp2f(c * -2.885390082f)), -1.f);
            float h  = oB * th;
            hbuf[t & 1][u] = (_Float16)h;          // matvec path (f16)
            hist[(t >> 6) & 1][t & 63][u] = h;     // head path (f32)
        }
        BARRIER();
        xs = xs_n;
    }

    // Tail: rows [T0, T) of the final (possibly partial) window.
    {
        const int T0 = ((T - 1) >> 6) << 6;
        if (hrow < T - T0) {
            const int buf = (T0 >> 6) & 1;
            float a = head_dot(&hist[buf][hrow][0], w_dense);
            orow[T0 + hrow] = a + bd;
        }
    }
}

extern "C" void kernel_launch(void* const* d_in, const int* in_sizes, int n_in,
                              void* d_out, int out_size, void* d_ws, size_t ws_size,
                              hipStream_t stream) {
    const float* x   = (const float*)d_in[0];
    const float* wih = (const float*)d_in[1];
    const float* whh = (const float*)d_in[2];
    const float* bih = (const float*)d_in[3];
    const float* bhh = (const float*)d_in[4];
    const float* wd  = (const float*)d_in[5];
    const float* bd  = (const float*)d_in[6];
    float* out = (float*)d_out;

    const int B = 32;
    const int T = in_sizes[0] / B;   // x is [B,T,1]

    lstm_fused<<<dim3(B), dim3(192), 0, stream>>>(x, wih, whh, bih, bhh, wd, bd, out, T);
}

// Round 8
// 8136.086 us; speedup vs baseline: 1.0413x; 1.0413x over previous
//
#include <hip/hip_runtime.h>

#define HID 96

typedef _Float16 h2 __attribute__((ext_vector_type(2)));

__device__ __forceinline__ h2 mkh2(float a, float b) {
    h2 r; r.x = (_Float16)a; r.y = (_Float16)b; return r;
}
__device__ __forceinline__ h2 bc(unsigned u) {
    union { unsigned u; h2 h; } c; c.u = u; return c.h;
}

// DPP quad-perm lane exchange (VALU, no LDS): 0xB1=xor1, 0x4E=xor2, 0x1B=xor3
template <int CTRL>
__device__ __forceinline__ float dpp_q(float v) {
    int i = __builtin_bit_cast(int, v);
    int r = __builtin_amdgcn_update_dpp(0, i, CTRL, 0xF, 0xF, true);
    return __builtin_bit_cast(float, r);
}

// 4 packed-dot2 steps: one uint4 (8 halves of h) against weight pairs A..D.
#define DOT4(Q, WA, WB, WC, WD) do {                                  \
    acc0 = __builtin_amdgcn_fdot2(W##WA, bc(Q.x), acc0, false);       \
    acc1 = __builtin_amdgcn_fdot2(W##WB, bc(Q.y), acc1, false);       \
    acc2 = __builtin_amdgcn_fdot2(W##WC, bc(Q.z), acc2, false);       \
    acc3 = __builtin_amdgcn_fdot2(W##WD, bc(Q.w), acc3, false);       \
} while (0)

// Barrier that drains ONLY LDS ops (lgkmcnt), leaving global prefetches
// (vmcnt) in flight.
#define BARRIER() asm volatile("s_waitcnt lgkmcnt(0)\n\ts_barrier" ::: "memory")

// 96-wide f32 dot of one LDS history row against w_dense.
__device__ __forceinline__ float head_dot(const float* hrow, const float* wdp) {
    const float4* hr = reinterpret_cast<const float4*>(hrow);
    const float4* wv = reinterpret_cast<const float4*>(wdp);
    float a0 = 0.f, a1 = 0.f, a2 = 0.f, a3 = 0.f;
    #pragma unroll
    for (int k = 0; k < 24; k += 4) {
        float4 ha = hr[k], hb = hr[k + 1], hc = hr[k + 2], hd = hr[k + 3];
        float4 wa = wv[k], wb = wv[k + 1], wc = wv[k + 2], wd = wv[k + 3];
        a0 = fmaf(ha.w, wa.w, fmaf(ha.z, wa.z, fmaf(ha.y, wa.y, fmaf(ha.x, wa.x, a0))));
        a1 = fmaf(hb.w, wb.w, fmaf(hb.z, wb.z, fmaf(hb.y, wb.y, fmaf(hb.x, wb.x, a1))));
        a2 = fmaf(hc.w, wc.w, fmaf(hc.z, wc.z, fmaf(hc.y, wc.y, fmaf(hc.x, wc.x, a2))));
        a3 = fmaf(hd.w, wd.w, fmaf(hd.z, wd.z, fmaf(hd.y, wd.y, fmaf(hd.x, wd.x, a3))));
    }
    return (a0 + a1) + (a2 + a3);
}

// 7 waves: 0..5 gate waves (quad layout lane = ((u&15)<<2)|g), 6 = head+stager.
// Gate waves have ZERO global-memory ops in the hot loop: x comes from LDS
// (staged 64 steps ahead by wave 6), weights are pinned resident in VGPRs.
__global__ __launch_bounds__(448)
void lstm_fused(
    const float* __restrict__ x,        // [B,T]
    const float* __restrict__ w_ih,     // [384]
    const float* __restrict__ w_hh,     // [384,96]
    const float* __restrict__ b_ih,     // [384]
    const float* __restrict__ b_hh,     // [384]
    const float* __restrict__ w_dense,  // [96]
    const float* __restrict__ b_dense,  // [1]
    float* __restrict__ out,            // [B,T]
    int T)
{
    const int tid  = threadIdx.x;    // 0..447
    const int lane = tid & 63;
    const int wv   = tid >> 6;       // 0..5 gate, 6 head

    // Double-buffered h (f16, broadcast-read).
    __shared__ __align__(16) _Float16 hbuf[2][96];
    // 64-step h history (f32) for the dense head.
    __shared__ __align__(16) float hist[2][64][100];
    // x staged per 64-step window (double-buffered), written by the head wave.
    __shared__ float xstage[2][64];

    if (tid < 96) { hbuf[0][tid] = (_Float16)0.f; hbuf[1][tid] = (_Float16)0.f; }

    const float* xrow = x + (size_t)blockIdx.x * T;
    float*       orow = out + (size_t)blockIdx.x * T;

    // Prime window 0 of xstage.
    if (tid < 64) xstage[0][tid] = (tid < T) ? xrow[tid] : 0.f;

    __syncthreads();

    if (wv < 6) {
        // ---- gate waves: quad layout — lane = ((u&15)<<2) | g ----
        const int g = lane & 3;                  // 0=i 1=f 2=g 3=o
        const int u = (wv << 4) | (lane >> 2);   // hidden unit 0..95
        const int j = g * 96 + u;                // w_hh row

        const float4* wr = reinterpret_cast<const float4*>(w_hh + (size_t)j * HID);
        float4 t0 = wr[0], t1 = wr[1], t2 = wr[2], t3 = wr[3], t4 = wr[4], t5 = wr[5];
        h2 W0  = mkh2(t0.x, t0.y),  W1  = mkh2(t0.z, t0.w);
        h2 W2  = mkh2(t1.x, t1.y),  W3  = mkh2(t1.z, t1.w);
        h2 W4  = mkh2(t2.x, t2.y),  W5  = mkh2(t2.z, t2.w);
        h2 W6  = mkh2(t3.x, t3.y),  W7  = mkh2(t3.z, t3.w);
        h2 W8  = mkh2(t4.x, t4.y),  W9  = mkh2(t4.z, t4.w);
        h2 W10 = mkh2(t5.x, t5.y),  W11 = mkh2(t5.z, t5.w);
        float4 s0 = wr[6], s1 = wr[7], s2 = wr[8], s3 = wr[9], s4 = wr[10], s5 = wr[11];
        h2 W12 = mkh2(s0.x, s0.y),  W13 = mkh2(s0.z, s0.w);
        h2 W14 = mkh2(s1.x, s1.y),  W15 = mkh2(s1.z, s1.w);
        h2 W16 = mkh2(s2.x, s2.y),  W17 = mkh2(s2.z, s2.w);
        h2 W18 = mkh2(s3.x, s3.y),  W19 = mkh2(s3.z, s3.w);
        h2 W20 = mkh2(s4.x, s4.y),  W21 = mkh2(s4.z, s4.w);
        h2 W22 = mkh2(s5.x, s5.y),  W23 = mkh2(s5.z, s5.w);
        float4 r0 = wr[12], r1 = wr[13], r2 = wr[14], r3 = wr[15], r4 = wr[16], r5 = wr[17];
        h2 W24 = mkh2(r0.x, r0.y),  W25 = mkh2(r0.z, r0.w);
        h2 W26 = mkh2(r1.x, r1.y),  W27 = mkh2(r1.z, r1.w);
        h2 W28 = mkh2(r2.x, r2.y),  W29 = mkh2(r2.z, r2.w);
        h2 W30 = mkh2(r3.x, r3.y),  W31 = mkh2(r3.z, r3.w);
        h2 W32 = mkh2(r4.x, r4.y),  W33 = mkh2(r4.z, r4.w);
        h2 W34 = mkh2(r5.x, r5.y),  W35 = mkh2(r5.z, r5.w);
        float4 q0 = wr[18], q1 = wr[19], q2 = wr[20], q3 = wr[21], q4 = wr[22], q5 = wr[23];
        h2 W36 = mkh2(q0.x, q0.y),  W37 = mkh2(q0.z, q0.w);
        h2 W38 = mkh2(q1.x, q1.y),  W39 = mkh2(q1.z, q1.w);
        h2 W40 = mkh2(q2.x, q2.y),  W41 = mkh2(q2.z, q2.w);
        h2 W42 = mkh2(q3.x, q3.y),  W43 = mkh2(q3.z, q3.w);
        h2 W44 = mkh2(q4.x, q4.y),  W45 = mkh2(q4.z, q4.w);
        h2 W46 = mkh2(q5.x, q5.y),  W47 = mkh2(q5.z, q5.w);

        const float wihr = w_ih[j];
        const float bias = b_ih[j] + b_hh[j];
        // gate g==2 is tanh = 2*sig(2x)-1; others sigmoid.
        const bool  isg = (g == 2);
        const float nk  = isg ? -2.885390082f : -1.442695041f;  // -s1*log2(e)
        const float m1  = isg ? 2.f : 1.f;
        const float d1  = isg ? -1.f : 0.f;

        float c  = 0.f;
        float xb = fmaf(xrow[0], wihr, bias);   // x-term folded one step ahead

        #pragma unroll 1
        for (int t = 0; t < T; ++t) {
            int tn = (t + 1 < T) ? t + 1 : T - 1;
            // Next-step x from LDS (broadcast read, consumed next iteration).
            float xs_n = xstage[(tn >> 6) & 1][tn & 63];
            float xb_n = fmaf(xs_n, wihr, bias);

            const uint4* hp = reinterpret_cast<const uint4*>(hbuf[(t & 1) ^ 1]);
            float acc0 = 0.f, acc1 = 0.f, acc2 = 0.f, acc3 = 0.f;
            uint4 qA = hp[0], qB = hp[1], qC = hp[2];
            DOT4(qA, 0, 1, 2, 3);     qA = hp[3];
            DOT4(qB, 4, 5, 6, 7);     qB = hp[4];
            DOT4(qC, 8, 9, 10, 11);   qC = hp[5];
            DOT4(qA, 12, 13, 14, 15); qA = hp[6];
            DOT4(qB, 16, 17, 18, 19); qB = hp[7];
            DOT4(qC, 20, 21, 22, 23); qC = hp[8];
            DOT4(qA, 24, 25, 26, 27); qA = hp[9];
            DOT4(qB, 28, 29, 30, 31); qB = hp[10];
            DOT4(qC, 32, 33, 34, 35); qC = hp[11];
            DOT4(qA, 36, 37, 38, 39);
            DOT4(qB, 40, 41, 42, 43);
            DOT4(qC, 44, 45, 46, 47);

            float v    = (acc0 + acc1) + (acc2 + acc3);
            float pre  = v + xb;
            float actv = fmaf(m1, __builtin_amdgcn_rcpf(1.f + __builtin_exp2f(pre * nk)), d1);

            // gather the other 3 gates of this unit via quad-perm DPP (VALU)
            float x1 = dpp_q<0xB1>(actv);   // lane^1
            float x2 = dpp_q<0x4E>(actv);   // lane^2
            float x3 = dpp_q<0x1B>(actv);   // lane^3

            if ((lane & 3) == 0) {   // i-lane owns unit u: actv=i, x1=f, x2=g, x3=o
                c = fmaf(x1, c, actv * x2);
                float th = fmaf(2.f, __builtin_amdgcn_rcpf(1.f + __builtin_exp2f(c * -2.885390082f)), -1.f);
                float h  = x3 * th;
                hbuf[t & 1][u] = (_Float16)h;          // matvec path (f16)
                hist[(t >> 6) & 1][t & 63][u] = h;     // head path (f32)
            }
            BARRIER();
            xb = xb_n;

            // Pin all 48 weight regs as loop-carried asm outputs: the compiler
            // cannot rematerialize them from memory (values are opaque).
            asm("" : "+v"(W0),  "+v"(W1),  "+v"(W2),  "+v"(W3),  "+v"(W4),  "+v"(W5),
                     "+v"(W6),  "+v"(W7),  "+v"(W8),  "+v"(W9),  "+v"(W10), "+v"(W11),
                     "+v"(W12), "+v"(W13), "+v"(W14), "+v"(W15), "+v"(W16), "+v"(W17),
                     "+v"(W18), "+v"(W19), "+v"(W20), "+v"(W21), "+v"(W22), "+v"(W23));
            asm("" : "+v"(W24), "+v"(W25), "+v"(W26), "+v"(W27), "+v"(W28), "+v"(W29),
                     "+v"(W30), "+v"(W31), "+v"(W32), "+v"(W33), "+v"(W34), "+v"(W35),
                     "+v"(W36), "+v"(W37), "+v"(W38), "+v"(W39), "+v"(W40), "+v"(W41),
                     "+v"(W42), "+v"(W43), "+v"(W44), "+v"(W45), "+v"(W46), "+v"(W47));
        }
    } else {
        // ---- head wave: x staging + one output burst per 64-step window ----
        const float bd = b_dense[0];
        float xg = (64 + lane < T) ? xrow[64 + lane] : 0.f;   // window 1

        #pragma unroll 1
        for (int t = 0; t < T; ++t) {
            if ((t & 63) == 0) {
                if (t) {
                    const int buf = ((t >> 6) - 1) & 1;    // completed window
                    float a = head_dot(&hist[buf][lane][0], w_dense);
                    orow[t - 64 + lane] = a + bd;
                }
                const int wnext = (t >> 6) + 1;
                if (wnext * 64 < T) {
                    xstage[wnext & 1][lane] = xg;          // stage next window
                    int nidx = (wnext + 1) * 64 + lane;    // prefetch window+2
                    xg = (nidx < T) ? xrow[nidx] : 0.f;
                }
            }
            BARRIER();
        }
        // tail: rows [T0, T)
        const int T0 = ((T - 1) >> 6) << 6;
        if (lane < T - T0) {
            const int buf = (T0 >> 6) & 1;
            float a = head_dot(&hist[buf][lane][0], w_dense);
            orow[T0 + lane] = a + bd;
        }
    }
}

extern "C" void kernel_launch(void* const* d_in, const int* in_sizes, int n_in,
                              void* d_out, int out_size, void* d_ws, size_t ws_size,
                              hipStream_t stream) {
    const float* x   = (const float*)d_in[0];
    const float* wih = (const float*)d_in[1];
    const float* whh = (const float*)d_in[2];
    const float* bih = (const float*)d_in[3];
    const float* bhh = (const float*)d_in[4];
    const float* wd  = (const float*)d_in[5];
    const float* bd  = (const float*)d_in[6];
    float* out = (float*)d_out;

    const int B = 32;
    const int T = in_sizes[0] / B;   // x is [B,T,1]

    lstm_fused<<<dim3(B), dim3(448), 0, stream>>>(x, wih, whh, bih, bhh, wd, bd, out, T);
}